// Round 2
// baseline (20382.544 us; speedup 1.0000x reference)
//
#include <hip/hip_runtime.h>

#define V 32000
#define D 256
#define H 256
#define T 128
#define B 32
#define SOS 126
#define H2 512

__device__ __forceinline__ float sigf(float x) { return 1.f / (1.f + __expf(-x)); }
__device__ __forceinline__ float ftanh(float x) {
    x = fminf(15.f, fmaxf(-15.f, x));
    float e = __expf(2.f * x);
    return (e - 1.f) / (e + 1.f);
}

// ---------------- embedding gather fused with transpose: ET[t][k][b]
// grid (128 t x 8 kb) x 256
__global__ __launch_bounds__(256) void k_embed_t(const int* __restrict__ x,
                                                 const float* __restrict__ emb,
                                                 float* __restrict__ ET) {
    __shared__ float s[32][33];
    int t = blockIdx.x >> 3, kb = blockIdx.x & 7;
    int tid = threadIdx.x;
    int lk = tid & 31, lb = tid >> 5;
#pragma unroll
    for (int i = 0; i < 4; ++i) {
        int b = lb + i * 8;
        s[b][lk] = emb[x[b * T + t] * D + kb * 32 + lk];
    }
    __syncthreads();
    int lb2 = tid & 31, lk2 = tid >> 5;
#pragma unroll
    for (int i = 0; i < 4; ++i) {
        int k = lk2 + i * 8;
        ET[t * (D * B) + (kb * 32 + k) * B + lb2] = s[lb2][k];
    }
}

// ---------------- generic LDS-tiled transpose: dst[C][R] from src[R][C]
__global__ __launch_bounds__(256) void k_tr(const float* __restrict__ src,
                                            float* __restrict__ dst, int R, int C) {
    __shared__ float tle[32][33];
    int rb = blockIdx.x * 32, cb = blockIdx.y * 32;
    int lr = threadIdx.x & 31, lc = threadIdx.x >> 5;
#pragma unroll
    for (int i = 0; i < 32; i += 8) tle[lc + i][lr] = src[(size_t)(rb + lc + i) * C + cb + lr];
    __syncthreads();
#pragma unroll
    for (int i = 0; i < 32; i += 8) dst[(size_t)(cb + lc + i) * R + rb + lr] = tle[lr][lc + i];
}

// ---------------- WencT[k][dir*1024 + u*4+g], k<256 from Wih, k>=256 from Whh
__global__ __launch_bounds__(256) void k_prep_encw(
    const float* __restrict__ Wih_f, const float* __restrict__ Whh_f,
    const float* __restrict__ Wih_b, const float* __restrict__ Whh_b,
    float* __restrict__ WencT) {
    int idx = blockIdx.x * 256 + threadIdx.x;     // 512*2048 = 1,048,576
    int k = idx >> 11, col = idx & 2047;
    int dir = col >> 10, cu = col & 1023;
    int u = cu >> 2, g = cu & 3;
    const float* Wih = dir ? Wih_b : Wih_f;
    const float* Whh = dir ? Whh_b : Whh_f;
    float v = (k < 256) ? Wih[(g * H + u) * D + k] : Whh[(g * H + u) * H + (k - 256)];
    WencT[idx] = v;
}

// ---------------- WdT[k][u*4+g], k<768 from Wih_d, k>=768 from Whh_d
__global__ __launch_bounds__(256) void k_prep_decw(const float* __restrict__ Wih_d,
                                                   const float* __restrict__ Whh_d,
                                                   float* __restrict__ WdT) {
    int idx = blockIdx.x * 256 + threadIdx.x;     // 1280*2048 = 2,621,440
    int k = idx >> 11, col = idx & 2047;
    int u = col >> 2, g = col & 3;
    float v = (k < 768) ? Wih_d[(size_t)(g * H2 + u) * 768 + k]
                        : Whh_d[(size_t)(g * H2 + u) * H2 + (k - 768)];
    WdT[idx] = v;
}

// ---------------- fused encoder step: gates mm + cell. grid 32 = rb(8) x bq(4)
__global__ __launch_bounds__(256) void k_enc_mm(
    const float* __restrict__ WencT, const float* __restrict__ ET,
    float* __restrict__ hencT, float* __restrict__ cencT, float* __restrict__ enc_out,
    const float* __restrict__ bih_f, const float* __restrict__ bhh_f,
    const float* __restrict__ bih_b, const float* __restrict__ bhh_b, int t) {
    __shared__ float zs[256 * 9];
    int tid = threadIdx.x;
    int rb = blockIdx.x & 7, bq = blockIdx.x >> 3;
    int pp = t & 1;
    int row = rb * 256 + tid;
    int dir = row >> 10, cu = row & 1023;
    int u = cu >> 2, g = cu & 3;
    int b0 = bq * 8;
    float bias = (dir ? bih_b : bih_f)[g * H + u] + (dir ? bhh_b : bhh_f)[g * H + u];

    float acc[8];
#pragma unroll
    for (int i = 0; i < 8; ++i) acc[i] = 0.f;
    const float* wp = WencT + row;
    const float* e0 = ET + t * (D * B) + b0;
    const float* h0p = hencT + pp * 16384 + dir * 8192 + b0;
#pragma unroll 4
    for (int k = 0; k < 256; ++k) {
        float w = wp[k * 2048];
#pragma unroll
        for (int i = 0; i < 8; ++i) acc[i] = fmaf(w, e0[k * 32 + i], acc[i]);
    }
#pragma unroll 4
    for (int k = 0; k < 256; ++k) {
        float w = wp[(256 + k) * 2048];
#pragma unroll
        for (int i = 0; i < 8; ++i) acc[i] = fmaf(w, h0p[k * 32 + i], acc[i]);
    }
#pragma unroll
    for (int i = 0; i < 8; ++i) zs[tid * 9 + i] = acc[i] + bias;
    __syncthreads();

#pragma unroll
    for (int j = 0; j < 2; ++j) {
        int item = tid + j * 256;
        int ul = item >> 3, bi = item & 7;
        float zi = zs[(ul * 4 + 0) * 9 + bi], zf = zs[(ul * 4 + 1) * 9 + bi];
        float zg = zs[(ul * 4 + 2) * 9 + bi], zo = zs[(ul * 4 + 3) * 9 + bi];
        int gu = (rb & 3) * 64 + ul;
        int b = b0 + bi;
        int ci = (dir * 256 + gu) * 32 + b;
        float c2 = sigf(zf) * cencT[ci] + sigf(zi) * ftanh(zg);
        cencT[ci] = c2;
        float h2 = sigf(zo) * ftanh(c2);
        hencT[(pp ^ 1) * 16384 + ci] = h2;
        enc_out[(b * T + t) * H2 + dir * H + gu] = h2;
    }
}

// ---------------- proj_e = enc_out @ Wa_e^T  (4096 x 512)@(512 x 512)^T
__global__ __launch_bounds__(256) void k_proj(const float* __restrict__ enc_out,
                                              const float* __restrict__ Wa_e,
                                              float* __restrict__ proj_e) {
    __shared__ float X[16][512];
    int tid = threadIdx.x;
    int r0 = blockIdx.x * 16;
    for (int i = tid; i < 16 * 512; i += 256) {
        int r = i >> 9, k = i & 511;
        X[r][k] = enc_out[(r0 + r) * H2 + k];
    }
    __syncthreads();
    int j0 = tid * 2;
    float acc0[16], acc1[16];
#pragma unroll
    for (int r = 0; r < 16; ++r) { acc0[r] = 0.f; acc1[r] = 0.f; }
    const float* w0 = Wa_e + j0 * H2;
    const float* w1 = Wa_e + (j0 + 1) * H2;
    for (int k = 0; k < H2; k += 4) {
        float4 wa = *(const float4*)(w0 + k);
        float4 wb = *(const float4*)(w1 + k);
#pragma unroll
        for (int r = 0; r < 16; ++r) {
            float4 xv = *(const float4*)(&X[r][k]);
            acc0[r] = fmaf(wa.x, xv.x, acc0[r]); acc0[r] = fmaf(wa.y, xv.y, acc0[r]);
            acc0[r] = fmaf(wa.z, xv.z, acc0[r]); acc0[r] = fmaf(wa.w, xv.w, acc0[r]);
            acc1[r] = fmaf(wb.x, xv.x, acc1[r]); acc1[r] = fmaf(wb.y, xv.y, acc1[r]);
            acc1[r] = fmaf(wb.z, xv.z, acc1[r]); acc1[r] = fmaf(wb.w, xv.w, acc1[r]);
        }
    }
#pragma unroll
    for (int r = 0; r < 16; ++r) {
        float2 st; st.x = acc0[r]; st.y = acc1[r];
        *(float2*)(proj_e + (r0 + r) * H2 + j0) = st;
    }
}

// ---------------- decoder init: hdecT/cdecT <- final encoder states (k-major copy)
__global__ __launch_bounds__(256) void k_init_dec(const float* __restrict__ hencT,
                                                  const float* __restrict__ cencT,
                                                  float* __restrict__ hdecT,
                                                  float* __restrict__ cdecT) {
    int idx = blockIdx.x * 256 + threadIdx.x;   // 16384
    hdecT[idx] = hencT[idx];                    // pp=0 after 128 steps
    cdecT[idx] = cencT[idx];
}

// ---------------- q0 = h0 @ Wa_h^T. grid 4 = jb(2) x bh(2)
__global__ __launch_bounds__(256) void k_qinit(const float* __restrict__ hdecT,
                                               const float* __restrict__ WahT,
                                               float* __restrict__ q_buf) {
    int tid = threadIdx.x;
    int jb = blockIdx.x & 1, bh = blockIdx.x >> 1;
    int j = jb * 256 + tid, b0 = bh * 16;
    float acc[16];
#pragma unroll
    for (int i = 0; i < 16; ++i) acc[i] = 0.f;
    const float* wp = WahT + j;
    const float* xp = hdecT + b0;
#pragma unroll 4
    for (int k = 0; k < H2; ++k) {
        float w = wp[k * H2];
#pragma unroll
        for (int i = 0; i < 16; ++i) acc[i] = fmaf(w, xp[k * 32 + i], acc[i]);
    }
#pragma unroll
    for (int i = 0; i < 16; ++i) q_buf[(b0 + i) * H2 + j] = acc[i];
}

// ---------------- K1: finalize prev step (argmax -> tok, lse) + attention + xcatT
// grid 32 (one per batch) x 512 threads. finalize=1: only phase 0.
__global__ __launch_bounds__(512) void k_attn(
    const float* __restrict__ proj_e, const float* __restrict__ enc_out,
    const float* __restrict__ emb_dec, const float* __restrict__ q_buf,
    const float* __restrict__ b_a, const float* __restrict__ v_a,
    const float* __restrict__ Pm, const float* __restrict__ Ps, const int* __restrict__ Pi,
    float* __restrict__ lse, float* __restrict__ xcatT, int t, int finalize) {
    __shared__ float rm[512]; __shared__ float rs[512]; __shared__ int ri[512];
    __shared__ float es[128]; __shared__ float wsm[128]; __shared__ float sred[128];
    __shared__ int tok_sh;
    int tid = threadIdx.x;
    int b = blockIdx.x;
    int tokb = SOS;

    if (t > 0) {
        float m = -INFINITY, s = 0.f; int mi = 0x7fffffff;
        if (tid < 500) { m = Pm[tid * 32 + b]; s = Ps[tid * 32 + b]; mi = Pi[tid * 32 + b]; }
        rm[tid] = m; rs[tid] = s; ri[tid] = mi;
        __syncthreads();
        for (int off = 256; off >= 1; off >>= 1) {
            if (tid < off) {
                float m1 = rm[tid], m2 = rm[tid + off];
                float s1 = rs[tid], s2 = rs[tid + off];
                int i1 = ri[tid], i2 = ri[tid + off];
                float m_, s_; int i_;
                if (m2 > m1)      { m_ = m2; s_ = s2 + s1 * __expf(m1 - m2); i_ = i2; }
                else if (m1 > m2) { m_ = m1; s_ = s1 + s2 * __expf(m2 - m1); i_ = i1; }
                else              { m_ = m1; s_ = s1 + s2; i_ = (i1 < i2) ? i1 : i2; }
                rm[tid] = m_; rs[tid] = s_; ri[tid] = i_;
            }
            __syncthreads();
        }
        if (tid == 0) {
            lse[b * T + (t - 1)] = rm[0] + logf(rs[0]);
            tok_sh = ri[0];
        }
        __syncthreads();
        tokb = tok_sh;
    }
    if (finalize) return;

    // phase 1: embedding -> xcatT rows [0,256)
    if (tid < 256) xcatT[tid * 32 + b] = emb_dec[tokb * D + tid];

    // phase 2: energy
    int l = tid & 63, w = tid >> 6;
    float q8[8], va8[8];
    {
        const float* qp = q_buf + b * H2 + l * 8;
        const float* bp = b_a + l * 8;
        const float* vp = v_a + l * 8;
#pragma unroll
        for (int j = 0; j < 8; ++j) { q8[j] = qp[j] + bp[j]; va8[j] = vp[j]; }
    }
    for (int tt = w; tt < T; tt += 8) {
        const float* pp = proj_e + (b * T + tt) * H2 + l * 8;
        float s = 0.f;
#pragma unroll
        for (int j = 0; j < 8; ++j) s += ftanh(pp[j] + q8[j]) * va8[j];
#pragma unroll
        for (int off = 32; off >= 1; off >>= 1) s += __shfl_xor(s, off);
        if (l == 0) es[tt] = s;
    }
    __syncthreads();

    // phase 3: softmax over T=128
    if (tid < 128) sred[tid] = es[tid];
    __syncthreads();
    for (int off = 64; off >= 1; off >>= 1) {
        if (tid < off) sred[tid] = fmaxf(sred[tid], sred[tid + off]);
        __syncthreads();
    }
    float M = sred[0];
    __syncthreads();
    float ev = 0.f;
    if (tid < 128) { ev = __expf(es[tid] - M); sred[tid] = ev; }
    __syncthreads();
    for (int off = 64; off >= 1; off >>= 1) {
        if (tid < off) sred[tid] += sred[tid + off];
        __syncthreads();
    }
    float S = sred[0];
    if (tid < 128) wsm[tid] = ev / S;
    __syncthreads();

    // phase 4: ctx -> xcatT rows [256,768)
    {
        int kk = tid;
        float acc = 0.f;
        const float* eo = enc_out + b * T * H2 + kk;
#pragma unroll 8
        for (int tt = 0; tt < T; ++tt) acc = fmaf(wsm[tt], eo[tt * H2], acc);
        xcatT[(256 + kk) * 32 + b] = acc;
    }
}

// ---------------- decoder gates mm (k-split). grid 128 = bh(2) x rb(8) x ks(8)
__global__ __launch_bounds__(256) void k_mm_dec(const float* __restrict__ WdT,
                                                const float* __restrict__ XdT,
                                                float* __restrict__ zp) {
    int tid = threadIdx.x;
    int bh = blockIdx.x & 1;
    int rb = (blockIdx.x >> 1) & 7;
    int ks = blockIdx.x >> 4;
    int row = rb * 256 + tid;
    int b0 = bh * 16;
    float acc[16];
#pragma unroll
    for (int i = 0; i < 16; ++i) acc[i] = 0.f;
    const float* wp = WdT + row;
    const float* xp = XdT + b0;
    int kbeg = ks * 160;
#pragma unroll 4
    for (int k = kbeg; k < kbeg + 160; ++k) {
        float w = wp[k * 2048];
#pragma unroll
        for (int i = 0; i < 16; ++i) acc[i] = fmaf(w, xp[k * 32 + i], acc[i]);
    }
    float* zo = zp + (size_t)(ks * 2048 + row) * 32 + b0;
#pragma unroll
    for (int i = 0; i < 16; i += 4) {
        float4 st; st.x = acc[i]; st.y = acc[i + 1]; st.z = acc[i + 2]; st.w = acc[i + 3];
        *(float4*)(zo + i) = st;
    }
}

// ---------------- decoder cell: reduce 8 k-split partials + LSTM cell. grid 64
__global__ __launch_bounds__(256) void k_cell_dec(const float* __restrict__ zp,
                                                  const float* __restrict__ bih_d,
                                                  const float* __restrict__ bhh_d,
                                                  float* __restrict__ cdecT,
                                                  float* __restrict__ hdecT) {
    int idx = blockIdx.x * 256 + threadIdx.x;   // 16384
    int u = idx >> 5, b = idx & 31;
    float z[4];
#pragma unroll
    for (int g = 0; g < 4; ++g) {
        float s = 0.f;
#pragma unroll
        for (int ks = 0; ks < 8; ++ks) s += zp[(size_t)(ks * 2048 + u * 4 + g) * 32 + b];
        z[g] = s + bih_d[g * H2 + u] + bhh_d[g * H2 + u];
    }
    float cp = cdecT[u * 32 + b];
    float c2 = sigf(z[1]) * cp + sigf(z[0]) * ftanh(z[2]);
    cdecT[u * 32 + b] = c2;
    float h2 = sigf(z[3]) * ftanh(c2);
    hdecT[u * 32 + b] = h2;
}

// ---------------- K3: logits (+ q piggyback). grid 254 = rblk(127) x bt(2)
__global__ __launch_bounds__(256) void k_logits(
    const float* __restrict__ WoutT, const float* __restrict__ WahT,
    const float* __restrict__ bout, const float* __restrict__ hdecT,
    float* __restrict__ out, float* __restrict__ q_buf,
    float* __restrict__ Pm, float* __restrict__ Ps, int* __restrict__ Pi, int t) {
    int tid = threadIdx.x;
    int bt = blockIdx.x & 1;
    int rblk = blockIdx.x >> 1;
    int row = rblk * 256 + tid;
    int b0 = bt * 16;
    const float* wp = (rblk < 125) ? (WoutT + row) : (WahT + (row - V));
    int wstride = (rblk < 125) ? V : H2;
    const float* xp = hdecT + b0;
    float acc[16];
#pragma unroll
    for (int i = 0; i < 16; ++i) acc[i] = 0.f;
#pragma unroll 4
    for (int k = 0; k < H2; ++k) {
        float w = wp[(size_t)k * wstride];
#pragma unroll
        for (int i = 0; i < 16; ++i) acc[i] = fmaf(w, xp[k * 32 + i], acc[i]);
    }
    if (rblk < 125) {
        float bo = bout[row];
        int l = tid & 63;
        int wt = rblk * 4 + (tid >> 6);
        float keep_m = 0.f, keep_s = 0.f; int keep_i = 0;
        for (int i = 0; i < 16; ++i) {
            float v = acc[i] + bo;
            out[((size_t)(b0 + i) * T + t) * V + row] = v;
            float m = v; int mi = row;
#pragma unroll
            for (int off = 1; off < 64; off <<= 1) {
                float om = __shfl_xor(m, off); int oi = __shfl_xor(mi, off);
                if (om > m || (om == m && oi < mi)) { m = om; mi = oi; }
            }
            float e = __expf(v - m);
#pragma unroll
            for (int off = 1; off < 64; off <<= 1) e += __shfl_xor(e, off);
            if (l == i) { keep_m = m; keep_i = mi; keep_s = e; }
        }
        if (l < 16) {
            Pm[wt * 32 + b0 + l] = keep_m;
            Ps[wt * 32 + b0 + l] = keep_s;
            Pi[wt * 32 + b0 + l] = keep_i;
        }
    } else {
        int jrow = row - V;
#pragma unroll
        for (int i = 0; i < 16; ++i) q_buf[(b0 + i) * H2 + jrow] = acc[i];
    }
}

// ---------------- final: out = logits - lse[b*T+t]
__global__ __launch_bounds__(256) void k_norm(float* __restrict__ out,
                                              const float* __restrict__ lse) {
    const int total4 = B * T * V / 4;   // 32,768,000
    int stride = gridDim.x * 256;
    for (int i4 = blockIdx.x * 256 + threadIdx.x; i4 < total4; i4 += stride) {
        int rowv = i4 / (V / 4);
        float l = lse[rowv];
        float4* p = (float4*)out + i4;
        float4 v = *p;
        v.x -= l; v.y -= l; v.z -= l; v.w -= l;
        *p = v;
    }
}

extern "C" void kernel_launch(void* const* d_in, const int* in_sizes, int n_in,
                              void* d_out, int out_size, void* d_ws, size_t ws_size,
                              hipStream_t stream) {
    const int* x          = (const int*)d_in[0];
    const float* emb_enc  = (const float*)d_in[1];
    const float* Wih_f    = (const float*)d_in[2];
    const float* Whh_f    = (const float*)d_in[3];
    const float* bih_f    = (const float*)d_in[4];
    const float* bhh_f    = (const float*)d_in[5];
    const float* Wih_b    = (const float*)d_in[6];
    const float* Whh_b    = (const float*)d_in[7];
    const float* bih_b    = (const float*)d_in[8];
    const float* bhh_b    = (const float*)d_in[9];
    const float* emb_dec  = (const float*)d_in[10];
    const float* Wa_h     = (const float*)d_in[11];
    const float* Wa_e     = (const float*)d_in[12];
    const float* v_a      = (const float*)d_in[13];
    const float* b_a      = (const float*)d_in[14];
    const float* Wih_d    = (const float*)d_in[15];
    const float* Whh_d    = (const float*)d_in[16];
    const float* bih_d    = (const float*)d_in[17];
    const float* bhh_d    = (const float*)d_in[18];
    const float* Wout     = (const float*)d_in[19];
    const float* bout     = (const float*)d_in[20];
    float* out = (float*)d_out;

    float* ws = (float*)d_ws;
    size_t o = 0;
    float* ET      = ws + o; o += (size_t)T * D * B;      // 1,048,576
    float* enc_out = ws + o; o += (size_t)B * T * H2;     // 2,097,152
    float* proj_e  = ws + o; o += (size_t)B * T * H2;     // 2,097,152
    float* WoutT   = ws + o; o += (size_t)H2 * V;         // 16,384,000
    float* WdT     = ws + o; o += (size_t)1280 * 2048;    // 2,621,440
    float* WencT   = ws + o; o += (size_t)512 * 2048;     // 1,048,576
    float* WahT    = ws + o; o += (size_t)H2 * H2;        // 262,144
    float* hencT   = ws + o; o += 2 * 16384;              // ping-pong [pp][dir][u][b]
    float* cencT   = ws + o; o += 16384;
    float* xcatT   = ws + o; o += 1280 * 32;              // rows 0..767 xcat, 768.. h
    float* cdecT   = ws + o; o += 16384;
    float* q_buf   = ws + o; o += 16384;
    float* zp      = ws + o; o += (size_t)8 * 2048 * 32;  // 524,288
    float* Pm      = ws + o; o += 16000;
    float* Ps      = ws + o; o += 16000;
    float* lse     = ws + o; o += 4096;
    int*   Pi      = (int*)(ws + o); o += 16000;
    float* hdecT   = xcatT + 768 * 32;

    // ---- one-time prep
    hipMemsetAsync(hencT, 0, (2 * 16384 + 16384) * sizeof(float), stream);
    k_embed_t<<<1024, 256, 0, stream>>>(x, emb_enc, ET);
    k_tr<<<dim3(1000, 16), 256, 0, stream>>>(Wout, WoutT, V, H2);
    k_tr<<<dim3(16, 16), 256, 0, stream>>>(Wa_h, WahT, H2, H2);
    k_prep_encw<<<4096, 256, 0, stream>>>(Wih_f, Whh_f, Wih_b, Whh_b, WencT);
    k_prep_decw<<<10240, 256, 0, stream>>>(Wih_d, Whh_d, WdT);

    // ---- encoder
    for (int t = 0; t < T; ++t)
        k_enc_mm<<<32, 256, 0, stream>>>(WencT, ET, hencT, cencT, enc_out,
                                         bih_f, bhh_f, bih_b, bhh_b, t);
    k_proj<<<256, 256, 0, stream>>>(enc_out, Wa_e, proj_e);
    k_init_dec<<<64, 256, 0, stream>>>(hencT, cencT, hdecT, cdecT);
    k_qinit<<<4, 256, 0, stream>>>(hdecT, WahT, q_buf);

    // ---- decoder
    for (int t = 0; t < T; ++t) {
        k_attn<<<32, 512, 0, stream>>>(proj_e, enc_out, emb_dec, q_buf, b_a, v_a,
                                       Pm, Ps, Pi, lse, xcatT, t, 0);
        k_mm_dec<<<128, 256, 0, stream>>>(WdT, xcatT, zp);
        k_cell_dec<<<64, 256, 0, stream>>>(zp, bih_d, bhh_d, cdecT, hdecT);
        k_logits<<<254, 256, 0, stream>>>(WoutT, WahT, bout, hdecT, out, q_buf,
                                          Pm, Ps, Pi, t);
    }
    k_attn<<<32, 512, 0, stream>>>(proj_e, enc_out, emb_dec, q_buf, b_a, v_a,
                                   Pm, Ps, Pi, lse, xcatT, T, 1);
    k_norm<<<4096, 256, 0, stream>>>(out, lse);
}